// Round 3
// baseline (3968.179 us; speedup 1.0000x reference)
//
#include <hip/hip_runtime.h>
#include <cstdint>
#include <cstddef>

// Problem dims (fixed by setup_inputs)
#define BB    2048   // batch
#define SS    256    // state dim
#define HH    256    // hidden dim
#define AA    2      // action dim
#define TT    50     // timesteps
#define NB    4      // batch rows per block
#define NBLK  512    // blocks (= BB/NB) -> 2 blocks/CU
#define NTHR  256    // threads per block

struct Params {
  const float* x;
  const float* fu[3]; const float* fv[3]; const float* fs[3];
  const float* f4u; const float* f4v; const float* f4s;
  const float* W[3]; const float* bs[3];
  const float* W4; const float* b4;
  float* out;
  float* wt2;         // [3][64 k4][256 h][4 k]  coalesced weight tiles
  float* partials;    // [2 slots][4 layers][6 stats][NBLK]
  unsigned* bar;      // [ctr, gen] (monotone)
  float* xT;          // [TT][BB*SS]  (optional)
  int use_xt;
};

__device__ __forceinline__ void pstore(float* p, float v) {
  __hip_atomic_store(p, v, __ATOMIC_RELAXED, __HIP_MEMORY_SCOPE_AGENT);
}
__device__ __forceinline__ float pload(const float* p) {
  return __hip_atomic_load(p, __ATOMIC_RELAXED, __HIP_MEMORY_SCOPE_AGENT);
}

// Split grid barrier (monotone generation; bar[0]=ctr, bar[1]=gen).
// All NBLK=512 blocks are co-resident (2/CU; VGPR<=256, tiny LDS).
__device__ __forceinline__ void bar_arrive(unsigned* bar, int b) {
  __syncthreads();
  if (threadIdx.x == 0) {
    unsigned old = __hip_atomic_fetch_add(bar, 1u, __ATOMIC_ACQ_REL, __HIP_MEMORY_SCOPE_AGENT);
    if (old == (unsigned)((b + 1) * NBLK - 1))
      __hip_atomic_store(bar + 1, (unsigned)(b + 1), __ATOMIC_RELEASE, __HIP_MEMORY_SCOPE_AGENT);
  }
}
__device__ __forceinline__ void bar_wait(unsigned* bar, int b) {
  if (threadIdx.x == 0) {
    while ((int)__hip_atomic_load(bar + 1, __ATOMIC_ACQUIRE, __HIP_MEMORY_SCOPE_AGENT) < b + 1)
      __builtin_amdgcn_s_sleep(2);
  }
  __syncthreads();
}

__global__ __launch_bounds__(NTHR, 2)
void snn_kernel(Params p) {
#pragma clang fp contract(off)
  const int tid  = threadIdx.x;
  const int blk  = blockIdx.x;
  const int gtid = blk * NTHR + tid;

  __shared__ __align__(16) float in_lds[HH * NB];   // [k][j] (input / spikes)
  __shared__ float wred[4][6];
  __shared__ float scal[4][2];                      // per-layer V_m, V_theta
  __shared__ float l4u[8], l4v[8], l4s[8], l4t[8], l4acc[8], l4vn[8], l4vth[8];

  // ------------- prologue 1: W -> coalesced k-tiled layout -------------
  // wt2[l][k4][h][q] = W[l][h][4*k4+q]; writes lane-consecutive (coalesced).
  if (gtid < 16384) {
    const int h = gtid & 255, k4 = gtid >> 8;   // k4: 0..63
    #pragma unroll
    for (int l = 0; l < 3; ++l) {
      float4 w = *reinterpret_cast<const float4*>(p.W[l] + (size_t)h * 256 + k4 * 4);
      *reinterpret_cast<float4*>(p.wt2 + (size_t)l * 65536 + (size_t)k4 * 1024 + h * 4) = w;
    }
  }
  // ------------- prologue 2: transpose x -> xT[t][b*SS+s] -------------
  if (p.use_xt) {
    for (int q = 0; q < 4; ++q) {
      int sid = gtid + q * (NBLK * NTHR);
      const float* src = p.x + (size_t)sid * TT;
      for (int t = 0; t < TT; ++t)
        p.xT[(size_t)t * (BB * SS) + sid] = src[t];
    }
  }

  // per-thread cells: 1 h x NB batch rows
  const int h0 = tid;  // 0..255

  float u[3][NB], v[3][NB], s[3][NB], tp[3][NB];
  #pragma unroll
  for (int l = 0; l < 3; ++l)
    #pragma unroll
    for (int j = 0; j < NB; ++j) {
      size_t idx = (size_t)(blk * NB + j) * HH + h0;
      u[l][j]  = p.fu[l][idx];
      v[l][j]  = p.fv[l][idx];
      s[l][j]  = p.fs[l][idx];
      tp[l][j] = 0.5f;
    }
  if (tid < 2 * NB) {
    int j = tid >> 1, a = tid & 1;
    size_t idx = (size_t)(blk * NB + j) * AA + a;
    l4u[tid] = p.f4u[idx]; l4v[tid] = p.f4v[idx]; l4s[tid] = p.f4s[idx];
    l4t[tid] = 0.5f; l4acc[tid] = 0.0f;
  }

  const float bL[3] = { p.bs[0][h0], p.bs[1][h0], p.bs[2][h0] };

  // init barrier: wt2 + xT visible everywhere (also covers l4 LDS init)
  bar_arrive(p.bar, 0);
  bar_wait(p.bar, 0);

  auto load_xt = [&](int t) {
    if (p.use_xt) {
      const float* base = p.xT + (size_t)t * (BB * SS) + (size_t)blk * NB * SS;
      float4 vv = make_float4(base[tid], base[SS + tid],
                              base[2 * SS + tid], base[3 * SS + tid]);
      *reinterpret_cast<float4*>(&in_lds[tid * NB]) = vv;
    } else {
      float4 vv = make_float4(
          p.x[((size_t)(blk * NB + 0) * SS + tid) * TT + t],
          p.x[((size_t)(blk * NB + 1) * SS + tid) * TT + t],
          p.x[((size_t)(blk * NB + 2) * SS + tid) * TT + t],
          p.x[((size_t)(blk * NB + 3) * SS + tid) * TT + t]);
      *reinterpret_cast<float4*>(&in_lds[tid * NB]) = vv;
    }
  };

  // GEMM: acc[j] += sum_k wt2[k][h0] * in[k][j], k ascending.
  // FMA chain order identical to previous rounds (bit-exact).
  auto gemm = [&](const float* __restrict__ wbase, float acc[NB]) {
    acc[0] = acc[1] = acc[2] = acc[3] = 0.0f;
    const float4* wp = reinterpret_cast<const float4*>(wbase + (h0 << 2));
    #pragma unroll 8
    for (int k4 = 0; k4 < 64; ++k4) {
      float4 w  = wp[(size_t)k4 << 8];   // wt2 + k4*1024 floats + h0*4
      float4 i0 = *reinterpret_cast<const float4*>(&in_lds[(k4 * 4 + 0) * NB]);
      float4 i1 = *reinterpret_cast<const float4*>(&in_lds[(k4 * 4 + 1) * NB]);
      float4 i2 = *reinterpret_cast<const float4*>(&in_lds[(k4 * 4 + 2) * NB]);
      float4 i3 = *reinterpret_cast<const float4*>(&in_lds[(k4 * 4 + 3) * NB]);
      acc[0] = fmaf(i0.x, w.x, acc[0]); acc[1] = fmaf(i0.y, w.x, acc[1]);
      acc[2] = fmaf(i0.z, w.x, acc[2]); acc[3] = fmaf(i0.w, w.x, acc[3]);
      acc[0] = fmaf(i1.x, w.y, acc[0]); acc[1] = fmaf(i1.y, w.y, acc[1]);
      acc[2] = fmaf(i1.z, w.y, acc[2]); acc[3] = fmaf(i1.w, w.y, acc[3]);
      acc[0] = fmaf(i2.x, w.z, acc[0]); acc[1] = fmaf(i2.y, w.z, acc[1]);
      acc[2] = fmaf(i2.z, w.z, acc[2]); acc[3] = fmaf(i2.w, w.z, acc[3]);
      acc[0] = fmaf(i3.x, w.w, acc[0]); acc[1] = fmaf(i3.y, w.w, acc[1]);
      acc[2] = fmaf(i3.z, w.w, acc[2]); acc[3] = fmaf(i3.w, w.w, acc[3]);
    }
  };

  load_xt(0);

  #pragma unroll 1
  for (int t = 0; t < TT; ++t) {
    __syncthreads();   // in_lds (x_t) ready

    // ---------------- layers 1..3 ----------------
    #pragma unroll
    for (int l = 0; l < 3; ++l) {
      float acc[NB];
      gemm(p.wt2 + (size_t)l * 65536, acc);

      if (l == 0 && t > 0) {
        // stats barrier for step t-1 — hidden behind the layer-1 GEMM above
        bar_wait(p.bar, t);
        {
          const int wv = tid >> 6, ln = tid & 63;
          const float* pb = p.partials + ((size_t)((t - 1) & 1) * 4 + wv) * 6 * NBLK;
          float r[6];
          #pragma unroll
          for (int st = 0; st < 6; ++st) {
            const float* q = pb + st * NBLK;
            float a0 = pload(q + ln),        a1 = pload(q + ln + 64);
            float a2 = pload(q + ln + 128),  a3 = pload(q + ln + 192);
            float a4 = pload(q + ln + 256),  a5 = pload(q + ln + 320);
            float a6 = pload(q + ln + 384),  a7 = pload(q + ln + 448);
            float rr;
            if (st == 0 || st == 3) {
              rr = ((((((a0 + a1) + a2) + a3) + a4) + a5) + a6) + a7;
              #pragma unroll
              for (int m = 1; m < 64; m <<= 1) rr += __shfl_xor(rr, m);
            } else if (st == 1 || st == 4) {
              rr = fmaxf(fmaxf(fmaxf(a0, a1), fmaxf(a2, a3)),
                         fmaxf(fmaxf(a4, a5), fmaxf(a6, a7)));
              #pragma unroll
              for (int m = 1; m < 64; m <<= 1) rr = fmaxf(rr, __shfl_xor(rr, m));
            } else {
              rr = fminf(fminf(fminf(a0, a1), fminf(a2, a3)),
                         fminf(fminf(a4, a5), fminf(a6, a7)));
              #pragma unroll
              for (int m = 1; m < 64; m <<= 1) rr = fminf(rr, __shfl_xor(rr, m));
            }
            r[st] = rr;
          }
          if (ln == 0) {
            const float invN = (wv == 3) ? (1.0f / 4096.0f) : (1.0f / 524288.0f);
            scal[wv][0] = (r[0] * invN) - 0.2f * (r[1] - r[2]);
            scal[wv][1] = (r[3] * invN) - 0.2f * (r[4] - r[5]);
          }
        }
        __syncthreads();
        // temporal updates for all layers from v(t-1) (still in regs / l4v)
        #pragma unroll
        for (int l2 = 0; l2 < 3; ++l2) {
          const float Vm = scal[l2][0], Vt = scal[l2][1];
          #pragma unroll
          for (int j = 0; j < NB; ++j) {
            float d  = v[l2][j] - Vm;
            float sp = logf(1.0f + expf(d * 0.25f));
            tp[l2][j] = (0.01f * d + Vt) + sp;
          }
        }
        if (tid < 2 * NB) {
          const float Vm = scal[3][0], Vt = scal[3][1];
          float d  = l4v[tid] - Vm;
          float sp = logf(1.0f + expf(d * 0.25f));
          l4t[tid] = (0.01f * d + Vt) + sp;
        }
        __syncthreads();  // l4t visible before layer-4 phase
      }

      // ---- LIF update + stats for layer l ----
      const float bbx = bL[l];
      float sv = 0.f, svt = 0.f;
      float mxv = -3.402823466e38f, mnv = 3.402823466e38f;
      float mxvt = -3.402823466e38f, mnvt = 3.402823466e38f;
      float sn[NB];
      #pragma unroll
      for (int j = 0; j < NB; ++j) {
        float un = fmaf(u[l][j], 0.5f, acc[j]) + bbx;
        float vp = v[l][j];
        float vd = (vp * 0.75f) * (1.0f - s[l][j]);
        float vn = vd + un;
        float en = expf((vp - vn) / 3.0f) - 1.0f;
        float vt = 0.5f * tp[l][j] + 0.5f * en;
        float sx = (vn > vt) ? 1.0f : 0.0f;
        u[l][j] = un; v[l][j] = vn; s[l][j] = sx;
        sn[j] = sx;
        sv += vn; svt += vt;
        mxv = fmaxf(mxv, vn); mnv = fminf(mnv, vn);
        mxvt = fmaxf(mxvt, vt); mnvt = fminf(mnvt, vt);
      }
      #pragma unroll
      for (int m = 1; m < 64; m <<= 1) {
        sv  += __shfl_xor(sv, m);   svt += __shfl_xor(svt, m);
        mxv  = fmaxf(mxv,  __shfl_xor(mxv, m));  mnv  = fminf(mnv,  __shfl_xor(mnv, m));
        mxvt = fmaxf(mxvt, __shfl_xor(mxvt, m)); mnvt = fminf(mnvt, __shfl_xor(mnvt, m));
      }
      __syncthreads();   // all GEMM reads of in_lds done; wred slot free
      if ((tid & 63) == 0) {
        int wv = tid >> 6;
        wred[wv][0] = sv;  wred[wv][1] = mxv;  wred[wv][2] = mnv;
        wred[wv][3] = svt; wred[wv][4] = mxvt; wred[wv][5] = mnvt;
      }
      // publish spikes as next layer's input
      *reinterpret_cast<float4*>(&in_lds[h0 * NB]) =
          make_float4(sn[0], sn[1], sn[2], sn[3]);
      __syncthreads();
      if (tid < 6) {
        int st = tid; float r;
        if (st == 0 || st == 3)
          r = ((wred[0][st] + wred[1][st]) + wred[2][st]) + wred[3][st];
        else if (st == 1 || st == 4)
          r = fmaxf(fmaxf(wred[0][st], wred[1][st]), fmaxf(wred[2][st], wred[3][st]));
        else
          r = fminf(fminf(wred[0][st], wred[1][st]), fminf(wred[2][st], wred[3][st]));
        pstore(&p.partials[(((size_t)(t & 1) * 4 + l) * 6 + st) * NBLK + blk], r);
      }
      __syncthreads();   // spikes + wred consumption complete
    }

    // ---------------- layer 4 (H -> 2) ----------------
    {
      const int g = tid >> 4, c = tid & 15;
      if (g < 2 * NB) {
        const int j4 = g >> 1, a4 = g & 1;
        float part = 0.0f;
        #pragma unroll
        for (int i = 0; i < 16; ++i) {
          int k = c + 16 * i;
          part = fmaf(in_lds[k * NB + j4], p.W4[a4 * HH + k], part);
        }
        #pragma unroll
        for (int m = 1; m < 16; m <<= 1) part += __shfl_xor(part, m);
        if (c == 0) {
          float un = fmaf(l4u[g], 0.5f, part) + p.b4[a4];
          float vp = l4v[g];
          float vd = (vp * 0.75f) * (1.0f - l4s[g]);
          float vn = vd + un;
          float en = expf((vp - vn) / 3.0f) - 1.0f;
          float vt = 0.5f * l4t[g] + 0.5f * en;
          float sx = (vn > vt) ? 1.0f : 0.0f;
          l4u[g] = un; l4v[g] = vn; l4s[g] = sx;
          l4acc[g] += sx; l4vn[g] = vn; l4vth[g] = vt;
        }
      }
    }
    __syncthreads();   // layer-4 reads of in_lds done; l4vn/l4vth visible

    if (t < TT - 1) load_xt(t + 1);   // writes in_lds (safe after sync)

    if (tid == 0) {
      float sv4 = l4vn[0], mx4 = l4vn[0], mn4 = l4vn[0];
      float st4 = l4vth[0], mxt4 = l4vth[0], mnt4 = l4vth[0];
      #pragma unroll
      for (int g2 = 1; g2 < 2 * NB; ++g2) {
        sv4 += l4vn[g2]; mx4 = fmaxf(mx4, l4vn[g2]); mn4 = fminf(mn4, l4vn[g2]);
        st4 += l4vth[g2]; mxt4 = fmaxf(mxt4, l4vth[g2]); mnt4 = fminf(mnt4, l4vth[g2]);
      }
      float* pp = p.partials + ((size_t)(t & 1) * 4 + 3) * 6 * NBLK + blk;
      pstore(pp + 0 * NBLK, sv4);  pstore(pp + 1 * NBLK, mx4);  pstore(pp + 2 * NBLK, mn4);
      pstore(pp + 3 * NBLK, st4);  pstore(pp + 4 * NBLK, mxt4); pstore(pp + 5 * NBLK, mnt4);
    }

    if (t < TT - 1) bar_arrive(p.bar, t + 1);  // includes __syncthreads
  }

  __syncthreads();
  if (tid < 2 * NB) {
    int j = tid >> 1, a = tid & 1;
    p.out[(size_t)(blk * NB + j) * AA + a] = l4acc[tid] / 50.0f;
  }
}

extern "C" void kernel_launch(void* const* d_in, const int* in_sizes, int n_in,
                              void* d_out, int out_size, void* d_ws, size_t ws_size,
                              hipStream_t stream) {
  Params p;
  p.x     = (const float*)d_in[0];
  p.fu[0] = (const float*)d_in[1];  p.fv[0] = (const float*)d_in[2];  p.fs[0] = (const float*)d_in[3];
  p.fu[1] = (const float*)d_in[4];  p.fv[1] = (const float*)d_in[5];  p.fs[1] = (const float*)d_in[6];
  p.fu[2] = (const float*)d_in[7];  p.fv[2] = (const float*)d_in[8];  p.fs[2] = (const float*)d_in[9];
  p.f4u   = (const float*)d_in[10]; p.f4v   = (const float*)d_in[11]; p.f4s   = (const float*)d_in[12];
  p.W[0]  = (const float*)d_in[13]; p.bs[0] = (const float*)d_in[14];
  p.W[1]  = (const float*)d_in[15]; p.bs[1] = (const float*)d_in[16];
  p.W[2]  = (const float*)d_in[17]; p.bs[2] = (const float*)d_in[18];
  p.W4    = (const float*)d_in[19]; p.b4    = (const float*)d_in[20];
  p.out   = (float*)d_out;

  float* ws   = (float*)d_ws;
  p.wt2       = ws;                        // 3*65536 = 196608 floats
  p.partials  = ws + 196608;               // 2*4*6*512 = 24576 floats
  p.bar       = (unsigned*)(ws + 221184);  // 2 uints (pad to 64)
  p.xT        = ws + 221248;               // 50*524288 floats (optional)
  size_t need = ((size_t)221248 + (size_t)TT * BB * SS) * sizeof(float);
  p.use_xt    = (ws_size >= need) ? 1 : 0;

  hipMemsetAsync((void*)p.bar, 0, 2 * sizeof(unsigned), stream);
  snn_kernel<<<dim3(NBLK), dim3(NTHR), 0, stream>>>(p);
}